// Round 1
// baseline (410.036 us; speedup 1.0000x reference)
//
#include <hip/hip_runtime.h>

#define IN_DIM  4096
#define OUT_DIM 1024
#define NN      4096
#define MM      8192
#define NSAMP   10

typedef __bf16 bf16x8 __attribute__((ext_vector_type(8)));
typedef float  fx4    __attribute__((ext_vector_type(4)));

__device__ __forceinline__ ushort f2bf(float f) {
    union { float f; unsigned u; } v; v.f = f;
    unsigned u = v.u;
    return (ushort)((u + 0x7FFFu + ((u >> 16) & 1u)) >> 16);
}
__device__ __forceinline__ float bf2f(ushort u) {
    union { unsigned u; float f; } v; v.u = ((unsigned)u) << 16;
    return v.f;
}

// async global->LDS, 16B per lane; LDS dest = wave-uniform base + lane*16
#define GLDS(g, l) __builtin_amdgcn_global_load_lds(                           \
    (const __attribute__((address_space(1))) unsigned*)(g),                    \
    (__attribute__((address_space(3))) unsigned*)(l), 16, 0, 0)

// ---------------------------------------------------------------------------
// K1: v1[k] = sum_o a1[o]*W[o,k];  v2[k] = sum_o a2[o]*W[o,k]
//     + fused: Wbf = bf16(W)  (W read exactly once here)
// grid (16,32): x = k-tile of 256, y = o-slice of 32; atomicAdd partials.
// ---------------------------------------------------------------------------
__global__ __launch_bounds__(256) void k_attvec(const float* __restrict__ W,
                                                const float* __restrict__ att,
                                                float* __restrict__ v1,
                                                float* __restrict__ v2,
                                                ushort* __restrict__ Wbf) {
    int k  = blockIdx.x * 256 + threadIdx.x;
    int o0 = blockIdx.y * 32;
    float s1 = 0.f, s2 = 0.f;
    for (int o = o0; o < o0 + 32; ++o) {
        float w = W[(size_t)o * IN_DIM + k];
        Wbf[(size_t)o * IN_DIM + k] = f2bf(w);
        s1 += att[o] * w;
        s2 += att[OUT_DIM + o] * w;
    }
    atomicAdd(&v1[k], s1);
    atomicAdd(&v2[k], s2);
}

// ---------------------------------------------------------------------------
// K2 (fused): one WAVE per row over NN + MM rows (4 rows per 256-thr block).
//   row < NN:  nalpha[row] = node_f[row,:] . v1
//   row >= NN: j = row-NN;  nbeta[j] = neigh_f[j,:] . v2  AND Abf[j,:] = bf16
// 16 independent float4 loads per lane -> deep MLP, no LDS, no __syncthreads.
// ---------------------------------------------------------------------------
__global__ __launch_bounds__(256) void k_rows(const float* __restrict__ node_f,
                                              const float* __restrict__ neigh_f,
                                              const float* __restrict__ v1,
                                              const float* __restrict__ v2,
                                              float* __restrict__ nalpha,
                                              float* __restrict__ nbeta,
                                              ushort* __restrict__ Abf) {
    int row  = blockIdx.x * 4 + (threadIdx.x >> 6);
    int lane = threadIdx.x & 63;
    float s = 0.f;
    if (row < NN) {
        const float4* xr = reinterpret_cast<const float4*>(node_f + (size_t)row * IN_DIM);
        const float4* vr = reinterpret_cast<const float4*>(v1);
#pragma unroll
        for (int i = lane; i < IN_DIM / 4; i += 64) {
            float4 a = xr[i], b = vr[i];
            s += a.x * b.x + a.y * b.y + a.z * b.z + a.w * b.w;
        }
    } else {
        int j = row - NN;
        const float4* xr = reinterpret_cast<const float4*>(neigh_f + (size_t)j * IN_DIM);
        const float4* vr = reinterpret_cast<const float4*>(v2);
        ushort4* yr = reinterpret_cast<ushort4*>(Abf + (size_t)j * IN_DIM);
#pragma unroll
        for (int i = lane; i < IN_DIM / 4; i += 64) {
            float4 a = xr[i], b = vr[i];
            s += a.x * b.x + a.y * b.y + a.z * b.z + a.w * b.w;
            ushort4 o;
            o.x = f2bf(a.x); o.y = f2bf(a.y); o.z = f2bf(a.z); o.w = f2bf(a.w);
            yr[i] = o;
        }
    }
#pragma unroll
    for (int off = 32; off > 0; off >>= 1) s += __shfl_down(s, off, 64);
    if (lane == 0) {
        if (row < NN) nalpha[row] = s; else nbeta[row - NN] = s;
    }
}

// ---------------------------------------------------------------------------
// K5: split-K x2 GEMM, 256x256 tile, BK=32, 4-deep circular LDS pipeline.
//   grid 256 blocks x 512 thr = 1 block/CU (128 KiB LDS), 8 waves (2M x 4N),
//   per-wave 128x64 output (8x4 16x16x32 bf16 MFMA frags).
// Pipeline (T3+T4): stage tile t+3 -> 12 swizzled ds_read_b128 -> 32 MFMA
//   (T5 setprio) -> s_waitcnt vmcnt(8) [tile t+1 landed; t+2/t+3 in flight]
//   -> raw s_barrier. vmcnt-before-barrier publishes ALL waves' staging.
//   Staging target buf[(t+3)&3] was last read in tile t-1, whose readers all
//   crossed the previous barrier -> race-free. Tail drains vmcnt 8->4->0.
// T2 swizzle (k-chunk ^= row&3): linear GLDS dest + inverse-swizzled GLOBAL
//   source + swizzled ds_read (rule #21). Breaks the 8-way row-stride-64B
//   bank conflict of the old kernel (8.4M conflict cycles -> ~0).
// T1 XCD swizzle: XCD c owns all 32 M-tiles of (N-tile=c&3, z=c>>2) -> its
//   1 MB B panel is L2-resident.
// Fragment layouts (HW-verified, learn_hip m89):
//   A/B operand: outer = lane&15, k = (lane>>4)*8 + j
//   C/D:         col   = lane&15, row = (lane>>4)*4 + reg
// ---------------------------------------------------------------------------
#define BMT 256
#define BNT 256
#define BKG 32
#define KSPLIT (IN_DIM / 2)
#define NT (KSPLIT / BKG)   // 64

__device__ __forceinline__ void tile_compute(const ushort* __restrict__ as,
                                             const ushort* __restrict__ bs,
                                             int aoff, int boff,
                                             fx4 (&acc)[8][4]) {
    bf16x8 af[8], bfr[4];
#pragma unroll
    for (int mi = 0; mi < 8; ++mi)
        af[mi] = *reinterpret_cast<const bf16x8*>(as + aoff + mi * 512);
#pragma unroll
    for (int ni = 0; ni < 4; ++ni)
        bfr[ni] = *reinterpret_cast<const bf16x8*>(bs + boff + ni * 512);
    __builtin_amdgcn_s_setprio(1);
#pragma unroll
    for (int mi = 0; mi < 8; ++mi)
#pragma unroll
        for (int ni = 0; ni < 4; ++ni)
            acc[mi][ni] = __builtin_amdgcn_mfma_f32_16x16x32_bf16(af[mi], bfr[ni], acc[mi][ni], 0, 0, 0);
    __builtin_amdgcn_s_setprio(0);
}

__global__ __launch_bounds__(512, 2) void k_gemm(const ushort* __restrict__ A,
                                                 const ushort* __restrict__ B,
                                                 ushort* __restrict__ P) {
    __shared__ __align__(16) ushort As[4][BMT * BKG];   // 4 x 16 KB
    __shared__ __align__(16) ushort Bs[4][BNT * BKG];   // 4 x 16 KB

    const int tid  = threadIdx.x;        // 0..511
    const int lane = tid & 63;
    const int wid  = tid >> 6;           // 0..7
    const int wr   = wid >> 2;           // 0..1  (M half)
    const int wc   = wid & 3;            // 0..3  (N quarter)
    const int lrow = lane & 15;
    const int q    = lane >> 4;

    // XCD-aware swizzle (bijective: 256 = 8 XCD * 32)
    const int bid = blockIdx.x;
    const int swz = (bid & 7) * 32 + (bid >> 3);
    const int tx  = swz & 31;            // M-tile 0..31
    const int ty  = (swz >> 5) & 3;      // N-tile 0..3
    const int tz  = swz >> 7;            // K-split 0..1
    const int bm  = tx * BMT;
    const int bn  = ty * BNT;
    const int kb  = tz * KSPLIT;

    // staging: thread tid covers 16B at linear LDS byte tid*16 (+8192 for the
    // second GLDS). row = tid>>2, k-chunk = tid&3; source chunk pre-swizzled.
    const int sr  = tid >> 2;                        // 0..127
    const int scu = (((tid & 3) ^ (sr & 3)) << 3);   // swizzled k offset (ushorts)
    const ushort* gA0 = A + (size_t)(bm + sr) * IN_DIM + kb + scu;
    const ushort* gA1 = gA0 + (size_t)128 * IN_DIM;
    const ushort* gB0 = B + (size_t)(bn + sr) * IN_DIM + kb + scu;
    const ushort* gB1 = gB0 + (size_t)128 * IN_DIM;
    const int wbase = wid * 512;                     // wave-uniform GLDS dest

#define STAGE(buf, kt) do {                                                    \
        GLDS(gA0 + (size_t)(kt) * BKG, &As[buf][0]        + wbase);            \
        GLDS(gA1 + (size_t)(kt) * BKG, &As[buf][0] + 4096 + wbase);            \
        GLDS(gB0 + (size_t)(kt) * BKG, &Bs[buf][0]        + wbase);            \
        GLDS(gB1 + (size_t)(kt) * BKG, &Bs[buf][0] + 4096 + wbase);            \
    } while (0)

    // read side: row R & 3 == lrow & 3 for every frag -> swizzled chunk is
    // thread-invariant: qs = (q ^ (lrow&3))*8 ushorts
    const int qs   = ((q ^ (lrow & 3)) << 3);
    const int aoff = (wr * 128 + lrow) * BKG + qs;   // + mi*512
    const int boff = (wc * 64  + lrow) * BKG + qs;   // + ni*512

    fx4 acc[8][4] = {};

    // prologue: stage tiles 0..2, make tile 0 visible
    STAGE(0, 0); STAGE(1, 1); STAGE(2, 2);
    asm volatile("s_waitcnt vmcnt(8)" ::: "memory");
    __builtin_amdgcn_s_barrier();

    for (int t = 0; t < NT - 3; ++t) {
        STAGE((t + 3) & 3, t + 3);
        tile_compute(&As[t & 3][0], &Bs[t & 3][0], aoff, boff, acc);
        asm volatile("s_waitcnt vmcnt(8)" ::: "memory");   // tile t+1 landed
        __builtin_amdgcn_s_barrier();
    }
    tile_compute(&As[(NT - 3) & 3][0], &Bs[(NT - 3) & 3][0], aoff, boff, acc);
    asm volatile("s_waitcnt vmcnt(4)" ::: "memory");       // tile NT-2 landed
    __builtin_amdgcn_s_barrier();
    tile_compute(&As[(NT - 2) & 3][0], &Bs[(NT - 2) & 3][0], aoff, boff, acc);
    asm volatile("s_waitcnt vmcnt(0)" ::: "memory");       // tile NT-1 landed
    __builtin_amdgcn_s_barrier();
    tile_compute(&As[(NT - 1) & 3][0], &Bs[(NT - 1) & 3][0], aoff, boff, acc);
#undef STAGE

    ushort* Pz = P + (size_t)tz * MM * OUT_DIM;
#pragma unroll
    for (int mi = 0; mi < 8; ++mi)
#pragma unroll
        for (int ni = 0; ni < 4; ++ni) {
            int r = bm + wr * 128 + mi * 16 + q * 4;
            int c = bn + wc * 64  + ni * 16 + lrow;
#pragma unroll
            for (int v = 0; v < 4; ++v)
                Pz[(size_t)(r + v) * OUT_DIM + c] = f2bf(acc[mi][ni][v]);
        }
}

// ---------------------------------------------------------------------------
// K6: parallel prologue — lanes 0..9 of wave 0 load idx/beta, dedupe via
// shfl (dup -> weight 0 == reference set semantics), softmax via shfl over
// 16 lanes.  Then all 256 threads gather: out = sum_t w_t*(P0[j_t]+P1[j_t]).
// ---------------------------------------------------------------------------
__global__ __launch_bounds__(256) void k_aggregate(const ushort* __restrict__ P,
                                                   const float* __restrict__ nalpha,
                                                   const float* __restrict__ nbeta,
                                                   const int* __restrict__ nidx,
                                                   float* __restrict__ outp) {
    int row = blockIdx.x;
    __shared__ int   s_idx[NSAMP];
    __shared__ float s_w[NSAMP];
    if (threadIdx.x < 16) {
        int t = threadIdx.x;
        int j = (t < NSAMP) ? nidx[row * NSAMP + t] : -1;
        float score = -INFINITY;
        if (t < NSAMP) {
            float x = nalpha[row] + nbeta[j];
            score = x > 0.f ? x : 0.2f * x;
        }
        bool dup = false;
#pragma unroll
        for (int sIdx = 0; sIdx < NSAMP; ++sIdx) {
            int js = __shfl(j, sIdx, 16);
            if (sIdx < t && js == j) dup = true;
        }
        float mx = score;
#pragma unroll
        for (int off = 8; off > 0; off >>= 1) {
            float o = __shfl_xor(mx, off, 16);
            mx = o > mx ? o : mx;
        }
        float e = (t < NSAMP && !dup) ? expf(score - mx) : 0.f;
        float sum = e;
#pragma unroll
        for (int off = 8; off > 0; off >>= 1) sum += __shfl_xor(sum, off, 16);
        if (t < NSAMP) {
            s_idx[t] = j;
            s_w[t]   = e / sum;
        }
    }
    __syncthreads();
    int col = threadIdx.x * 4;
    float ax = 0.f, ay = 0.f, az = 0.f, aw = 0.f;
#pragma unroll
    for (int t = 0; t < NSAMP; ++t) {
        float w = s_w[t];
        size_t off = (size_t)s_idx[t] * OUT_DIM + col;
        ushort4 u0 = *reinterpret_cast<const ushort4*>(P + off);
        ushort4 u1 = *reinterpret_cast<const ushort4*>(P + (size_t)MM * OUT_DIM + off);
        ax += w * (bf2f(u0.x) + bf2f(u1.x));
        ay += w * (bf2f(u0.y) + bf2f(u1.y));
        az += w * (bf2f(u0.z) + bf2f(u1.z));
        aw += w * (bf2f(u0.w) + bf2f(u1.w));
    }
    float4 o; o.x = ax; o.y = ay; o.z = az; o.w = aw;
    *reinterpret_cast<float4*>(outp + (size_t)row * OUT_DIM + col) = o;
}

// ---------------------------------------------------------------------------
extern "C" void kernel_launch(void* const* d_in, const int* in_sizes, int n_in,
                              void* d_out, int out_size, void* d_ws, size_t ws_size,
                              hipStream_t stream) {
    const float* node_f  = (const float*)d_in[0];  // 4096 x 4096
    const float* neigh_f = (const float*)d_in[1];  // 8192 x 4096
    const float* W       = (const float*)d_in[2];  // 1024 x 4096
    const float* att     = (const float*)d_in[3];  // 2048
    const int*   nidx    = (const int*)d_in[4];    // 4096 x 10
    float* outp = (float*)d_out;                   // 4096 x 1024 fp32

    char* ws = (char*)d_ws;
    ushort* Abf = (ushort*)ws;                     // 64 MB bf16 A
    ushort* Wbf = (ushort*)(ws + 67108864);        // 8 MB  bf16 W
    ushort* P   = (ushort*)(ws + 75497472);        // 2 x 16 MB bf16 partials
    float*  v1     = (float*)(ws + 109051904);
    float*  v2     = v1 + IN_DIM;
    float*  nalpha = v2 + IN_DIM;
    float*  nbeta  = nalpha + NN;

    hipMemsetAsync(v1, 0, 2 * IN_DIM * sizeof(float), stream);

    k_attvec   <<<dim3(16, 32),   256, 0, stream>>>(W, att, v1, v2, Wbf);
    k_rows     <<<(NN + MM) / 4,  256, 0, stream>>>(node_f, neigh_f, v1, v2, nalpha, nbeta, Abf);
    k_gemm     <<<256,            512, 0, stream>>>(Abf, Wbf, P);
    k_aggregate<<<NN,             256, 0, stream>>>(P, nalpha, nbeta, nidx, outp);
}

// Round 2
// 406.136 us; speedup vs baseline: 1.0096x; 1.0096x over previous
//
#include <hip/hip_runtime.h>

#define IN_DIM  4096
#define OUT_DIM 1024
#define NN      4096
#define MM      8192
#define NSAMP   10

typedef __bf16 bf16x8 __attribute__((ext_vector_type(8)));
typedef float  fx4    __attribute__((ext_vector_type(4)));

__device__ __forceinline__ ushort f2bf(float f) {
    union { float f; unsigned u; } v; v.f = f;
    unsigned u = v.u;
    return (ushort)((u + 0x7FFFu + ((u >> 16) & 1u)) >> 16);
}
__device__ __forceinline__ float bf2f(ushort u) {
    union { unsigned u; float f; } v; v.u = ((unsigned)u) << 16;
    return v.f;
}

// async global->LDS, 16B per lane; LDS dest = wave-uniform base + lane*16
#define GLDS(g, l) __builtin_amdgcn_global_load_lds(                           \
    (const __attribute__((address_space(1))) unsigned*)(g),                    \
    (__attribute__((address_space(3))) unsigned*)(l), 16, 0, 0)

#define VMWAIT(N) asm volatile("s_waitcnt vmcnt(" #N ")" ::: "memory")

// ---------------------------------------------------------------------------
// K1: v1[k] = sum_o a1[o]*W[o,k];  v2[k] = sum_o a2[o]*W[o,k]
//     + fused: Wbf = bf16(W)  (W read exactly once here)
// grid (16,64): x = k-tile of 256, y = o-slice of 16; atomicAdd partials.
// ---------------------------------------------------------------------------
__global__ __launch_bounds__(256) void k_attvec(const float* __restrict__ W,
                                                const float* __restrict__ att,
                                                float* __restrict__ v1,
                                                float* __restrict__ v2,
                                                ushort* __restrict__ Wbf) {
    int k  = blockIdx.x * 256 + threadIdx.x;
    int o0 = blockIdx.y * 16;
    float s1 = 0.f, s2 = 0.f;
#pragma unroll
    for (int o = o0; o < o0 + 16; ++o) {
        float w = W[(size_t)o * IN_DIM + k];
        Wbf[(size_t)o * IN_DIM + k] = f2bf(w);
        s1 += att[o] * w;
        s2 += att[OUT_DIM + o] * w;
    }
    atomicAdd(&v1[k], s1);
    atomicAdd(&v2[k], s2);
}

// ---------------------------------------------------------------------------
// K2 (fused): one WAVE per row over NN + MM rows (4 rows per 256-thr block).
//   row < NN:  nalpha[row] = node_f[row,:] . v1
//   row >= NN: j = row-NN;  nbeta[j] = neigh_f[j,:] . v2  AND Abf[j,:] = bf16
// ---------------------------------------------------------------------------
__global__ __launch_bounds__(256) void k_rows(const float* __restrict__ node_f,
                                              const float* __restrict__ neigh_f,
                                              const float* __restrict__ v1,
                                              const float* __restrict__ v2,
                                              float* __restrict__ nalpha,
                                              float* __restrict__ nbeta,
                                              ushort* __restrict__ Abf) {
    int row  = blockIdx.x * 4 + (threadIdx.x >> 6);
    int lane = threadIdx.x & 63;
    float s = 0.f;
    if (row < NN) {
        const float4* xr = reinterpret_cast<const float4*>(node_f + (size_t)row * IN_DIM);
        const float4* vr = reinterpret_cast<const float4*>(v1);
#pragma unroll
        for (int i = lane; i < IN_DIM / 4; i += 64) {
            float4 a = xr[i], b = vr[i];
            s += a.x * b.x + a.y * b.y + a.z * b.z + a.w * b.w;
        }
    } else {
        int j = row - NN;
        const float4* xr = reinterpret_cast<const float4*>(neigh_f + (size_t)j * IN_DIM);
        const float4* vr = reinterpret_cast<const float4*>(v2);
        ushort4* yr = reinterpret_cast<ushort4*>(Abf + (size_t)j * IN_DIM);
#pragma unroll
        for (int i = lane; i < IN_DIM / 4; i += 64) {
            float4 a = xr[i], b = vr[i];
            s += a.x * b.x + a.y * b.y + a.z * b.z + a.w * b.w;
            ushort4 o;
            o.x = f2bf(a.x); o.y = f2bf(a.y); o.z = f2bf(a.z); o.w = f2bf(a.w);
            yr[i] = o;
        }
    }
#pragma unroll
    for (int off = 32; off > 0; off >>= 1) s += __shfl_down(s, off, 64);
    if (lane == 0) {
        if (row < NN) nalpha[row] = s; else nbeta[row - NN] = s;
    }
}

// ---------------------------------------------------------------------------
// K5: split-K x2 GEMM, 256x256 tile, BK=32, ring-4 LDS, 2-phase-per-tile
// barrier-paired schedule (m201 port):
//   phase A: ds_read af[0..3]+bfr[0..3] | GLDS A-halves(t+2) | barrier |
//            setprio(1) 16 MFMA (mi 0-3) setprio(0) | barrier
//   phase B: ds_read af[4..7] (bfr kept in regs) | GLDS B-halves(t+2) |
//            vmcnt(4) [retires exactly tile t+1's 4 loads -> landed] |
//            barrier | 16 MFMA (mi 4-7) | barrier
// Counted vmcnt once per tile, never 0 in steady state (T4). Ring-4 gives
// tile t+1 one full tile (~4 phase windows) of load slack. Buffer (t+2)&3
// was last read in tile t-2 => 2 barriers before restage => race-free.
// T2 swizzle (CORRECTED): chunk ^= (row>>1)&3. slot=(row&1)*4+chunk: rows
// 0..7 hit all 8 distinct 16B slots per 8-lane group => conflict-free
// (round-0 no-swz = 4-way, round-1 row&3 = 2-way extra; both measured 4/read).
// Linear GLDS dest + inverse-swizzled global source + swizzled read (#21).
// T1 XCD swizzle: XCD c owns all 32 M-tiles of one (N-tile,z) -> B panel
// (1MB) L2-resident.
// Fragment layouts (HW-verified, learn_hip m89):
//   A/B operand: outer = lane&15, k = (lane>>4)*8 + j
//   C/D:         col   = lane&15, row = (lane>>4)*4 + reg
// ---------------------------------------------------------------------------
#define BMT 256
#define BNT 256
#define BKG 32
#define KSPLIT (IN_DIM / 2)
#define NT (KSPLIT / BKG)   // 64

#define MF(x, y, mi, ni) acc[mi][ni] = __builtin_amdgcn_mfma_f32_16x16x32_bf16((x), (y), acc[mi][ni], 0, 0, 0)

__global__ __launch_bounds__(512, 2) void k_gemm(const ushort* __restrict__ A,
                                                 const ushort* __restrict__ B,
                                                 ushort* __restrict__ P) {
    __shared__ __align__(16) ushort As[4][BMT * BKG];   // 4 x 16 KB
    __shared__ __align__(16) ushort Bs[4][BNT * BKG];   // 4 x 16 KB

    const int tid  = threadIdx.x;        // 0..511
    const int lane = tid & 63;
    const int wid  = tid >> 6;           // 0..7
    const int wr   = wid >> 2;           // 0..1  (M half)
    const int wc   = wid & 3;            // 0..3  (N quarter)
    const int lrow = lane & 15;
    const int q    = lane >> 4;

    // XCD-aware swizzle (bijective: 256 = 8 XCD * 32)
    const int bid = blockIdx.x;
    const int swz = (bid & 7) * 32 + (bid >> 3);
    const int tx  = swz & 31;            // M-tile 0..31
    const int ty  = (swz >> 5) & 3;      // N-tile 0..3
    const int tz  = swz >> 7;            // K-split 0..1
    const int bm  = tx * BMT;
    const int bn  = ty * BNT;
    const int kb  = tz * KSPLIT;

    // staging: thread tid covers 16B at linear LDS byte tid*16 per GLDS op.
    // row = tid>>2 (one op = 128 rows x 64B), chunk = tid&3;
    // source chunk pre-swizzled with the involution chunk ^= (row>>1)&3.
    const int sr  = tid >> 2;                             // 0..127
    const int scu = (((tid & 3) ^ ((sr >> 1) & 3)) << 3); // swizzled k off (ushorts)
    const ushort* gA0 = A + (size_t)(bm + sr) * IN_DIM + kb + scu;
    const ushort* gA1 = gA0 + (size_t)128 * IN_DIM;
    const ushort* gB0 = B + (size_t)(bn + sr) * IN_DIM + kb + scu;
    const ushort* gB1 = gB0 + (size_t)128 * IN_DIM;
    const int wbase = wid * 512;                          // wave-uniform GLDS dest

#define STAGE_FULL(buf, kt) do {                                               \
        GLDS(gA0 + (size_t)(kt) * BKG, &As[buf][0]        + wbase);            \
        GLDS(gA1 + (size_t)(kt) * BKG, &As[buf][0] + 4096 + wbase);            \
        GLDS(gB0 + (size_t)(kt) * BKG, &Bs[buf][0]        + wbase);            \
        GLDS(gB1 + (size_t)(kt) * BKG, &Bs[buf][0] + 4096 + wbase);            \
    } while (0)

    // read side: frag row = base + lrow, base multiple of 16 => swizzle term
    // ((row>>1)&3) == ((lrow>>1)&3), thread-invariant across mi/ni.
    const int qs   = ((q ^ ((lrow >> 1) & 3)) << 3);
    const int aoff = (wr * 128 + lrow) * BKG + qs;   // + mi*512
    const int boff = (wc * 64  + lrow) * BKG + qs;   // + ni*512

    fx4 acc[8][4] = {};

    // prologue: stage tiles 0,1; wait tile 0 landed (4 newest may fly)
    STAGE_FULL(0, 0);
    STAGE_FULL(1, 1);
    VMWAIT(4);
    __builtin_amdgcn_s_barrier();
    asm volatile("" ::: "memory");

    // WAITK_: 0 -> vmcnt(4) (steady), 1 -> vmcnt(0) (drain), 2 -> none
#define TILE_BODY(t_, STG_, WAITK_) do {                                       \
        const int bt_ = (t_) & 3;                                              \
        const ushort* as_ = &As[bt_][0];                                       \
        const ushort* bs_ = &Bs[bt_][0];                                       \
        bf16x8 a0, a1, a2, a3, b0, b1, b2, b3;                                 \
        a0 = *reinterpret_cast<const bf16x8*>(as_ + aoff + 0 * 512);           \
        a1 = *reinterpret_cast<const bf16x8*>(as_ + aoff + 1 * 512);           \
        a2 = *reinterpret_cast<const bf16x8*>(as_ + aoff + 2 * 512);           \
        a3 = *reinterpret_cast<const bf16x8*>(as_ + aoff + 3 * 512);           \
        b0 = *reinterpret_cast<const bf16x8*>(bs_ + boff + 0 * 512);           \
        b1 = *reinterpret_cast<const bf16x8*>(bs_ + boff + 1 * 512);           \
        b2 = *reinterpret_cast<const bf16x8*>(bs_ + boff + 2 * 512);           \
        b3 = *reinterpret_cast<const bf16x8*>(bs_ + boff + 3 * 512);           \
        if (STG_) {                                                            \
            ushort* d_ = &As[((t_) + 2) & 3][0] + wbase;                       \
            GLDS(gA0 + (size_t)((t_) + 2) * BKG, d_);                         \
            GLDS(gA1 + (size_t)((t_) + 2) * BKG, d_ + 4096);                  \
        }                                                                      \
        __builtin_amdgcn_s_barrier();                                          \
        asm volatile("" ::: "memory");                                         \
        __builtin_amdgcn_s_setprio(1);                                         \
        MF(a0, b0, 0, 0); MF(a0, b1, 0, 1); MF(a0, b2, 0, 2); MF(a0, b3, 0, 3);\
        MF(a1, b0, 1, 0); MF(a1, b1, 1, 1); MF(a1, b2, 1, 2); MF(a1, b3, 1, 3);\
        MF(a2, b0, 2, 0); MF(a2, b1, 2, 1); MF(a2, b2, 2, 2); MF(a2, b3, 2, 3);\
        MF(a3, b0, 3, 0); MF(a3, b1, 3, 1); MF(a3, b2, 3, 2); MF(a3, b3, 3, 3);\
        __builtin_amdgcn_s_setprio(0);                                         \
        __builtin_amdgcn_s_barrier();                                          \
        asm volatile("" ::: "memory");                                         \
        a0 = *reinterpret_cast<const bf16x8*>(as_ + aoff + 4 * 512);           \
        a1 = *reinterpret_cast<const bf16x8*>(as_ + aoff + 5 * 512);           \
        a2 = *reinterpret_cast<const bf16x8*>(as_ + aoff + 6 * 512);           \
        a3 = *reinterpret_cast<const bf16x8*>(as_ + aoff + 7 * 512);           \
        if (STG_) {                                                            \
            ushort* d_ = &Bs[((t_) + 2) & 3][0] + wbase;                       \
            GLDS(gB0 + (size_t)((t_) + 2) * BKG, d_);                         \
            GLDS(gB1 + (size_t)((t_) + 2) * BKG, d_ + 4096);                  \
        }                                                                      \
        if ((WAITK_) == 0) { VMWAIT(4); } else if ((WAITK_) == 1) { VMWAIT(0); }\
        __builtin_amdgcn_s_barrier();                                          \
        asm volatile("" ::: "memory");                                         \
        __builtin_amdgcn_s_setprio(1);                                         \
        MF(a0, b0, 4, 0); MF(a0, b1, 4, 1); MF(a0, b2, 4, 2); MF(a0, b3, 4, 3);\
        MF(a1, b0, 5, 0); MF(a1, b1, 5, 1); MF(a1, b2, 5, 2); MF(a1, b3, 5, 3);\
        MF(a2, b0, 6, 0); MF(a2, b1, 6, 1); MF(a2, b2, 6, 2); MF(a2, b3, 6, 3);\
        MF(a3, b0, 7, 0); MF(a3, b1, 7, 1); MF(a3, b2, 7, 2); MF(a3, b3, 7, 3);\
        __builtin_amdgcn_s_setprio(0);                                         \
        __builtin_amdgcn_s_barrier();                                          \
        asm volatile("" ::: "memory");                                         \
    } while (0)

    for (int t = 0; t < NT - 2; ++t)
        TILE_BODY(t, 1, 0);
    TILE_BODY(NT - 2, 0, 1);
    TILE_BODY(NT - 1, 0, 2);
#undef TILE_BODY
#undef STAGE_FULL

    ushort* Pz = P + (size_t)tz * MM * OUT_DIM;
#pragma unroll
    for (int mi = 0; mi < 8; ++mi)
#pragma unroll
        for (int ni = 0; ni < 4; ++ni) {
            int r = bm + wr * 128 + mi * 16 + q * 4;
            int c = bn + wc * 64  + ni * 16 + lrow;
#pragma unroll
            for (int v = 0; v < 4; ++v)
                Pz[(size_t)(r + v) * OUT_DIM + c] = f2bf(acc[mi][ni][v]);
        }
}

// ---------------------------------------------------------------------------
// K6: parallel prologue — lanes 0..9 of wave 0 load idx/beta, dedupe via
// shfl (dup -> weight 0 == reference set semantics), softmax via shfl over
// 16 lanes.  Then all 256 threads gather: out = sum_t w_t*(P0[j_t]+P1[j_t]).
// ---------------------------------------------------------------------------
__global__ __launch_bounds__(256) void k_aggregate(const ushort* __restrict__ P,
                                                   const float* __restrict__ nalpha,
                                                   const float* __restrict__ nbeta,
                                                   const int* __restrict__ nidx,
                                                   float* __restrict__ outp) {
    int row = blockIdx.x;
    __shared__ int   s_idx[NSAMP];
    __shared__ float s_w[NSAMP];
    if (threadIdx.x < 16) {
        int t = threadIdx.x;
        int j = (t < NSAMP) ? nidx[row * NSAMP + t] : -1;
        float score = -INFINITY;
        if (t < NSAMP) {
            float x = nalpha[row] + nbeta[j];
            score = x > 0.f ? x : 0.2f * x;
        }
        bool dup = false;
#pragma unroll
        for (int sIdx = 0; sIdx < NSAMP; ++sIdx) {
            int js = __shfl(j, sIdx, 16);
            if (sIdx < t && js == j) dup = true;
        }
        float mx = score;
#pragma unroll
        for (int off = 8; off > 0; off >>= 1) {
            float o = __shfl_xor(mx, off, 16);
            mx = o > mx ? o : mx;
        }
        float e = (t < NSAMP && !dup) ? expf(score - mx) : 0.f;
        float sum = e;
#pragma unroll
        for (int off = 8; off > 0; off >>= 1) sum += __shfl_xor(sum, off, 16);
        if (t < NSAMP) {
            s_idx[t] = j;
            s_w[t]   = e / sum;
        }
    }
    __syncthreads();
    int col = threadIdx.x * 4;
    float ax = 0.f, ay = 0.f, az = 0.f, aw = 0.f;
#pragma unroll
    for (int t = 0; t < NSAMP; ++t) {
        float w = s_w[t];
        size_t off = (size_t)s_idx[t] * OUT_DIM + col;
        ushort4 u0 = *reinterpret_cast<const ushort4*>(P + off);
        ushort4 u1 = *reinterpret_cast<const ushort4*>(P + (size_t)MM * OUT_DIM + off);
        ax += w * (bf2f(u0.x) + bf2f(u1.x));
        ay += w * (bf2f(u0.y) + bf2f(u1.y));
        az += w * (bf2f(u0.z) + bf2f(u1.z));
        aw += w * (bf2f(u0.w) + bf2f(u1.w));
    }
    float4 o; o.x = ax; o.y = ay; o.z = az; o.w = aw;
    *reinterpret_cast<float4*>(outp + (size_t)row * OUT_DIM + col) = o;
}

// ---------------------------------------------------------------------------
extern "C" void kernel_launch(void* const* d_in, const int* in_sizes, int n_in,
                              void* d_out, int out_size, void* d_ws, size_t ws_size,
                              hipStream_t stream) {
    const float* node_f  = (const float*)d_in[0];  // 4096 x 4096
    const float* neigh_f = (const float*)d_in[1];  // 8192 x 4096
    const float* W       = (const float*)d_in[2];  // 1024 x 4096
    const float* att     = (const float*)d_in[3];  // 2048
    const int*   nidx    = (const int*)d_in[4];    // 4096 x 10
    float* outp = (float*)d_out;                   // 4096 x 1024 fp32

    char* ws = (char*)d_ws;
    ushort* Abf = (ushort*)ws;                     // 64 MB bf16 A
    ushort* Wbf = (ushort*)(ws + 67108864);        // 8 MB  bf16 W
    ushort* P   = (ushort*)(ws + 75497472);        // 2 x 16 MB bf16 partials
    float*  v1     = (float*)(ws + 109051904);
    float*  v2     = v1 + IN_DIM;
    float*  nalpha = v2 + IN_DIM;
    float*  nbeta  = nalpha + NN;

    hipMemsetAsync(v1, 0, 2 * IN_DIM * sizeof(float), stream);

    k_attvec   <<<dim3(16, 64),   256, 0, stream>>>(W, att, v1, v2, Wbf);
    k_rows     <<<(NN + MM) / 4,  256, 0, stream>>>(node_f, neigh_f, v1, v2, nalpha, nbeta, Abf);
    k_gemm     <<<256,            512, 0, stream>>>(Abf, Wbf, P);
    k_aggregate<<<NN,             256, 0, stream>>>(P, nalpha, nbeta, nidx, outp);
}

// Round 3
// 395.245 us; speedup vs baseline: 1.0374x; 1.0276x over previous
//
#include <hip/hip_runtime.h>

#define IN_DIM  4096
#define OUT_DIM 1024
#define NN      4096
#define MM      8192
#define NSAMP   10

typedef __bf16 bf16x8 __attribute__((ext_vector_type(8)));
typedef float  fx4    __attribute__((ext_vector_type(4)));

__device__ __forceinline__ ushort f2bf(float f) {
    union { float f; unsigned u; } v; v.f = f;
    unsigned u = v.u;
    return (ushort)((u + 0x7FFFu + ((u >> 16) & 1u)) >> 16);
}
__device__ __forceinline__ float bf2f(ushort u) {
    union { unsigned u; float f; } v; v.u = ((unsigned)u) << 16;
    return v.f;
}

// async global->LDS, 16B per lane; LDS dest = wave-uniform base + lane*16
#define GLDS(g, l) __builtin_amdgcn_global_load_lds(                           \
    (const __attribute__((address_space(1))) unsigned*)(g),                    \
    (__attribute__((address_space(3))) unsigned*)(l), 16, 0, 0)

// ---------------------------------------------------------------------------
// K1: v1[k] = sum_o a1[o]*W[o,k];  v2[k] = sum_o a2[o]*W[o,k]
//     + fused: Wbf = bf16(W)  (W read exactly once here)
// grid (16,64): x = k-tile of 256, y = o-slice of 16; atomicAdd partials.
// ---------------------------------------------------------------------------
__global__ __launch_bounds__(256) void k_attvec(const float* __restrict__ W,
                                                const float* __restrict__ att,
                                                float* __restrict__ v1,
                                                float* __restrict__ v2,
                                                ushort* __restrict__ Wbf) {
    int k  = blockIdx.x * 256 + threadIdx.x;
    int o0 = blockIdx.y * 16;
    float s1 = 0.f, s2 = 0.f;
#pragma unroll
    for (int o = o0; o < o0 + 16; ++o) {
        float w = W[(size_t)o * IN_DIM + k];
        Wbf[(size_t)o * IN_DIM + k] = f2bf(w);
        s1 += att[o] * w;
        s2 += att[OUT_DIM + o] * w;
    }
    atomicAdd(&v1[k], s1);
    atomicAdd(&v2[k], s2);
}

// ---------------------------------------------------------------------------
// K2 (fused): one WAVE per row over NN + MM rows (4 rows per 256-thr block).
//   row < NN:  nalpha[row] = node_f[row,:] . v1
//   row >= NN: j = row-NN;  nbeta[j] = neigh_f[j,:] . v2  AND Abf[j,:] = bf16
// ---------------------------------------------------------------------------
__global__ __launch_bounds__(256) void k_rows(const float* __restrict__ node_f,
                                              const float* __restrict__ neigh_f,
                                              const float* __restrict__ v1,
                                              const float* __restrict__ v2,
                                              float* __restrict__ nalpha,
                                              float* __restrict__ nbeta,
                                              ushort* __restrict__ Abf) {
    int row  = blockIdx.x * 4 + (threadIdx.x >> 6);
    int lane = threadIdx.x & 63;
    float s = 0.f;
    if (row < NN) {
        const float4* xr = reinterpret_cast<const float4*>(node_f + (size_t)row * IN_DIM);
        const float4* vr = reinterpret_cast<const float4*>(v1);
#pragma unroll
        for (int i = lane; i < IN_DIM / 4; i += 64) {
            float4 a = xr[i], b = vr[i];
            s += a.x * b.x + a.y * b.y + a.z * b.z + a.w * b.w;
        }
    } else {
        int j = row - NN;
        const float4* xr = reinterpret_cast<const float4*>(neigh_f + (size_t)j * IN_DIM);
        const float4* vr = reinterpret_cast<const float4*>(v2);
        ushort4* yr = reinterpret_cast<ushort4*>(Abf + (size_t)j * IN_DIM);
#pragma unroll
        for (int i = lane; i < IN_DIM / 4; i += 64) {
            float4 a = xr[i], b = vr[i];
            s += a.x * b.x + a.y * b.y + a.z * b.z + a.w * b.w;
            ushort4 o;
            o.x = f2bf(a.x); o.y = f2bf(a.y); o.z = f2bf(a.z); o.w = f2bf(a.w);
            yr[i] = o;
        }
    }
#pragma unroll
    for (int off = 32; off > 0; off >>= 1) s += __shfl_down(s, off, 64);
    if (lane == 0) {
        if (row < NN) nalpha[row] = s; else nbeta[row - NN] = s;
    }
}

// ---------------------------------------------------------------------------
// K5: split-K x2 GEMM — r0 proven structure (128x128 tile, 4 waves 2x2 of
// 64x64, 256 thr, ~4 blocks/CU cross-block overlap) with three in-family
// deltas:
//  * BK=64 (32 KiB LDS): halves syncthreads/vmcnt-drain count (32 K-tiles).
//  * Conflict-free XOR swizzle: LDS rows are 128 B = 8 x 16B chunks;
//    LDS(r,c) holds global chunk c^(r&7). Stage: linear GLDS dest, source
//    chunk = (lane&7)^(lane>>3) (sr&7 == lane>>3). Read: chunk
//    ((q|s*4)^(lrow&7)) -> lanes 8g..8g+7 hit 8 distinct chunks (was 8-way).
//  * Bijective XCD swizzle: 1D grid 1024; XCD c gets 2 B-panels (1 MB,
//    L2-resident).
// Fragment layouts (HW-verified, learn_hip m89):
//   A/B operand: outer = lane&15, k = (lane>>4)*8 + j  (k-step s adds s*32)
//   C/D:         col   = lane&15, row = (lane>>4)*4 + reg
// ---------------------------------------------------------------------------
#define TM 128
#define TN 128
#define BK 64
#define KSPLIT (IN_DIM / 2)

__global__ __launch_bounds__(256, 4) void k_gemm(const ushort* __restrict__ A,
                                                 const ushort* __restrict__ B,
                                                 ushort* __restrict__ P) {
    __shared__ __align__(16) ushort As[TM * BK];   // 16 KB
    __shared__ __align__(16) ushort Bs[TN * BK];   // 16 KB
    const int tid  = threadIdx.x;
    const int lane = tid & 63;
    const int wave = tid >> 6;
    const int wm   = (wave >> 1) * 64;
    const int wn   = (wave & 1) * 64;
    const int lrow = lane & 15;
    const int q    = lane >> 4;

    // XCD-aware bijective swizzle: 1024 blocks = 8 XCD * 128
    const int bid = blockIdx.x;
    const int wg  = (bid & 7) * 128 + (bid >> 3);
    const int bx  = wg & 63;             // M-tile
    const int by  = (wg >> 6) & 7;       // N-tile
    const int bz  = wg >> 9;             // K-split
    const int bm  = bx * TM;
    const int bn  = by * TN;
    const int kb  = bz * KSPLIT;

    // staging: wave w covers rows w*32 + (lane>>3) + 8i, chunk lane&7.
    // source chunk pre-swizzled: g = (lane&7) ^ (sr&7), sr&7 == lane>>3.
    const int sr  = wave * 32 + (lane >> 3);
    const int sco = (((lane & 7) ^ (lane >> 3)) << 3);   // ushort offset
    const ushort* gA = A + (size_t)(bm + sr) * IN_DIM + kb + sco;
    const ushort* gB = B + (size_t)(bn + sr) * IN_DIM + kb + sco;
    ushort* lA = As + wave * 2048;
    ushort* lB = Bs + wave * 2048;

    // read-side swizzled chunk offset (ushorts): step s flips bit2 (^32)
    const int c0u = ((q ^ (lrow & 7)) << 3);

    fx4 acc[4][4] = {};

    for (int k0 = 0; k0 < KSPLIT; k0 += BK) {
#pragma unroll
        for (int i = 0; i < 4; ++i)
            GLDS(gA + k0 + (size_t)i * 8 * IN_DIM, lA + i * 512);
#pragma unroll
        for (int i = 0; i < 4; ++i)
            GLDS(gB + k0 + (size_t)i * 8 * IN_DIM, lB + i * 512);
        __syncthreads();

#pragma unroll
        for (int s = 0; s < 2; ++s) {
            const int co = c0u ^ (s << 5);
            bf16x8 af[4], bfr[4];
#pragma unroll
            for (int mi = 0; mi < 4; ++mi)
                af[mi] = *reinterpret_cast<const bf16x8*>(As + (wm + mi * 16 + lrow) * BK + co);
#pragma unroll
            for (int ni = 0; ni < 4; ++ni)
                bfr[ni] = *reinterpret_cast<const bf16x8*>(Bs + (wn + ni * 16 + lrow) * BK + co);
#pragma unroll
            for (int mi = 0; mi < 4; ++mi)
#pragma unroll
                for (int ni = 0; ni < 4; ++ni)
                    acc[mi][ni] = __builtin_amdgcn_mfma_f32_16x16x32_bf16(af[mi], bfr[ni], acc[mi][ni], 0, 0, 0);
        }
        __syncthreads();
    }

    ushort* Pz = P + (size_t)bz * MM * OUT_DIM;
#pragma unroll
    for (int mi = 0; mi < 4; ++mi)
#pragma unroll
        for (int ni = 0; ni < 4; ++ni) {
            int r = bm + wm + mi * 16 + q * 4;
            int c = bn + wn + ni * 16 + lrow;
#pragma unroll
            for (int v = 0; v < 4; ++v)
                Pz[(size_t)(r + v) * OUT_DIM + c] = f2bf(acc[mi][ni][v]);
        }
}

// ---------------------------------------------------------------------------
// K6: parallel prologue — lanes 0..9 of wave 0 load idx/beta, dedupe via
// shfl (dup -> weight 0 == reference set semantics), softmax via shfl over
// 16 lanes.  Then all 256 threads gather: out = sum_t w_t*(P0[j_t]+P1[j_t]).
// ---------------------------------------------------------------------------
__global__ __launch_bounds__(256) void k_aggregate(const ushort* __restrict__ P,
                                                   const float* __restrict__ nalpha,
                                                   const float* __restrict__ nbeta,
                                                   const int* __restrict__ nidx,
                                                   float* __restrict__ outp) {
    int row = blockIdx.x;
    __shared__ int   s_idx[NSAMP];
    __shared__ float s_w[NSAMP];
    if (threadIdx.x < 16) {
        int t = threadIdx.x;
        int j = (t < NSAMP) ? nidx[row * NSAMP + t] : -1;
        float score = -INFINITY;
        if (t < NSAMP) {
            float x = nalpha[row] + nbeta[j];
            score = x > 0.f ? x : 0.2f * x;
        }
        bool dup = false;
#pragma unroll
        for (int sIdx = 0; sIdx < NSAMP; ++sIdx) {
            int js = __shfl(j, sIdx, 16);
            if (sIdx < t && js == j) dup = true;
        }
        float mx = score;
#pragma unroll
        for (int off = 8; off > 0; off >>= 1) {
            float o = __shfl_xor(mx, off, 16);
            mx = o > mx ? o : mx;
        }
        float e = (t < NSAMP && !dup) ? expf(score - mx) : 0.f;
        float sum = e;
#pragma unroll
        for (int off = 8; off > 0; off >>= 1) sum += __shfl_xor(sum, off, 16);
        if (t < NSAMP) {
            s_idx[t] = j;
            s_w[t]   = e / sum;
        }
    }
    __syncthreads();
    int col = threadIdx.x * 4;
    float ax = 0.f, ay = 0.f, az = 0.f, aw = 0.f;
#pragma unroll
    for (int t = 0; t < NSAMP; ++t) {
        float w = s_w[t];
        size_t off = (size_t)s_idx[t] * OUT_DIM + col;
        ushort4 u0 = *reinterpret_cast<const ushort4*>(P + off);
        ushort4 u1 = *reinterpret_cast<const ushort4*>(P + (size_t)MM * OUT_DIM + off);
        ax += w * (bf2f(u0.x) + bf2f(u1.x));
        ay += w * (bf2f(u0.y) + bf2f(u1.y));
        az += w * (bf2f(u0.z) + bf2f(u1.z));
        aw += w * (bf2f(u0.w) + bf2f(u1.w));
    }
    float4 o; o.x = ax; o.y = ay; o.z = az; o.w = aw;
    *reinterpret_cast<float4*>(outp + (size_t)row * OUT_DIM + col) = o;
}

// ---------------------------------------------------------------------------
extern "C" void kernel_launch(void* const* d_in, const int* in_sizes, int n_in,
                              void* d_out, int out_size, void* d_ws, size_t ws_size,
                              hipStream_t stream) {
    const float* node_f  = (const float*)d_in[0];  // 4096 x 4096
    const float* neigh_f = (const float*)d_in[1];  // 8192 x 4096
    const float* W       = (const float*)d_in[2];  // 1024 x 4096
    const float* att     = (const float*)d_in[3];  // 2048
    const int*   nidx    = (const int*)d_in[4];    // 4096 x 10
    float* outp = (float*)d_out;                   // 4096 x 1024 fp32

    char* ws = (char*)d_ws;
    ushort* Abf = (ushort*)ws;                     // 64 MB bf16 A
    ushort* Wbf = (ushort*)(ws + 67108864);        // 8 MB  bf16 W
    ushort* P   = (ushort*)(ws + 75497472);        // 2 x 16 MB bf16 partials
    float*  v1     = (float*)(ws + 109051904);
    float*  v2     = v1 + IN_DIM;
    float*  nalpha = v2 + IN_DIM;
    float*  nbeta  = nalpha + NN;

    hipMemsetAsync(v1, 0, 2 * IN_DIM * sizeof(float), stream);

    k_attvec   <<<dim3(16, 64),   256, 0, stream>>>(W, att, v1, v2, Wbf);
    k_rows     <<<(NN + MM) / 4,  256, 0, stream>>>(node_f, neigh_f, v1, v2, nalpha, nbeta, Abf);
    k_gemm     <<<1024,           256, 0, stream>>>(Abf, Wbf, P);
    k_aggregate<<<NN,             256, 0, stream>>>(P, nalpha, nbeta, nidx, outp);
}

// Round 4
// 369.434 us; speedup vs baseline: 1.1099x; 1.0699x over previous
//
#include <hip/hip_runtime.h>

#define IN_DIM  4096
#define OUT_DIM 1024
#define NN      4096
#define MM      8192
#define NSAMP   10

typedef __bf16 bf16x8 __attribute__((ext_vector_type(8)));
typedef float  fx4    __attribute__((ext_vector_type(4)));

__device__ __forceinline__ ushort f2bf(float f) {
    union { float f; unsigned u; } v; v.f = f;
    unsigned u = v.u;
    return (ushort)((u + 0x7FFFu + ((u >> 16) & 1u)) >> 16);
}
__device__ __forceinline__ float bf2f(ushort u) {
    union { unsigned u; float f; } v; v.u = ((unsigned)u) << 16;
    return v.f;
}

// async global->LDS, 16B per lane; LDS dest = wave-uniform base + lane*16
#define GLDS(g, l) __builtin_amdgcn_global_load_lds(                           \
    (const __attribute__((address_space(1))) unsigned*)(g),                    \
    (__attribute__((address_space(3))) unsigned*)(l), 16, 0, 0)

// ---------------------------------------------------------------------------
// K1: v1[k] = sum_o a1[o]*W[o,k];  v2[k] = sum_o a2[o]*W[o,k]
//     + fused: Wbf = bf16(W)  (W read exactly once here)
// grid (16,64): x = k-tile of 256, y = o-slice of 16; atomicAdd partials.
// ---------------------------------------------------------------------------
__global__ __launch_bounds__(256) void k_attvec(const float* __restrict__ W,
                                                const float* __restrict__ att,
                                                float* __restrict__ v1,
                                                float* __restrict__ v2,
                                                ushort* __restrict__ Wbf) {
    int k  = blockIdx.x * 256 + threadIdx.x;
    int o0 = blockIdx.y * 16;
    float s1 = 0.f, s2 = 0.f;
#pragma unroll
    for (int o = o0; o < o0 + 16; ++o) {
        float w = W[(size_t)o * IN_DIM + k];
        Wbf[(size_t)o * IN_DIM + k] = f2bf(w);
        s1 += att[o] * w;
        s2 += att[OUT_DIM + o] * w;
    }
    atomicAdd(&v1[k], s1);
    atomicAdd(&v2[k], s2);
}

// ---------------------------------------------------------------------------
// K2 (fused): one WAVE per row over NN + MM rows (4 rows per 256-thr block).
//   row < NN:  nalpha[row] = node_f[row,:] . v1
//   row >= NN: j = row-NN;  nbeta[j] = neigh_f[j,:] . v2  AND Abf[j,:] = bf16
// ---------------------------------------------------------------------------
__global__ __launch_bounds__(256) void k_rows(const float* __restrict__ node_f,
                                              const float* __restrict__ neigh_f,
                                              const float* __restrict__ v1,
                                              const float* __restrict__ v2,
                                              float* __restrict__ nalpha,
                                              float* __restrict__ nbeta,
                                              ushort* __restrict__ Abf) {
    int row  = blockIdx.x * 4 + (threadIdx.x >> 6);
    int lane = threadIdx.x & 63;
    float s = 0.f;
    if (row < NN) {
        const float4* xr = reinterpret_cast<const float4*>(node_f + (size_t)row * IN_DIM);
        const float4* vr = reinterpret_cast<const float4*>(v1);
#pragma unroll
        for (int i = lane; i < IN_DIM / 4; i += 64) {
            float4 a = xr[i], b = vr[i];
            s += a.x * b.x + a.y * b.y + a.z * b.z + a.w * b.w;
        }
    } else {
        int j = row - NN;
        const float4* xr = reinterpret_cast<const float4*>(neigh_f + (size_t)j * IN_DIM);
        const float4* vr = reinterpret_cast<const float4*>(v2);
        ushort4* yr = reinterpret_cast<ushort4*>(Abf + (size_t)j * IN_DIM);
#pragma unroll
        for (int i = lane; i < IN_DIM / 4; i += 64) {
            float4 a = xr[i], b = vr[i];
            s += a.x * b.x + a.y * b.y + a.z * b.z + a.w * b.w;
            ushort4 o;
            o.x = f2bf(a.x); o.y = f2bf(a.y); o.z = f2bf(a.z); o.w = f2bf(a.w);
            yr[i] = o;
        }
    }
#pragma unroll
    for (int off = 32; off > 0; off >>= 1) s += __shfl_down(s, off, 64);
    if (lane == 0) {
        if (row < NN) nalpha[row] = s; else nbeta[row - NN] = s;
    }
}

// ---------------------------------------------------------------------------
// K5: split-K x2 GEMM — r0 structure (128x128 tile, 4 waves 2x2 of 64x64,
// 256 thr, ~4 blocks/CU) + BK=64 + conflict-free LDS swizzle.
// Block mapping: DEFAULT dim3(64,8,2), x = M-tile fastest. Linear id =
// bx + 64*by + 512*bz -> XCD = bx&7: each 512KB A-panel is read by exactly
// ONE XCD (all by,bz of that bx residue) -> A (64 MB, the big operand)
// fetched from HBM once. B (8 MB) broadcast-fetched; L2 absorbs most.
// (Round-3 lesson: the inverted mapping fetched A 4x = 271 MB, -15% perf.)
//  * BK=64 (32 KiB LDS): halves syncthreads/vmcnt-drain count (32 K-tiles).
//  * Conflict-free XOR swizzle (verified 0 conflict cycles r3): LDS rows are
//    128 B = 8 x 16B chunks; LDS(r,c) holds global chunk c^(r&7). Stage:
//    linear GLDS dest, source chunk = (lane&7)^(lane>>3). Read: chunk
//    (q|s*4)^(lrow&7) -> 8-lane groups hit 8 distinct chunks.
// Fragment layouts (HW-verified, learn_hip m89):
//   A/B operand: outer = lane&15, k = (lane>>4)*8 + j  (k-step s adds s*32)
//   C/D:         col   = lane&15, row = (lane>>4)*4 + reg
// ---------------------------------------------------------------------------
#define TM 128
#define TN 128
#define BK 64
#define KSPLIT (IN_DIM / 2)

__global__ __launch_bounds__(256, 4) void k_gemm(const ushort* __restrict__ A,
                                                 const ushort* __restrict__ B,
                                                 ushort* __restrict__ P) {
    __shared__ __align__(16) ushort As[TM * BK];   // 16 KB
    __shared__ __align__(16) ushort Bs[TN * BK];   // 16 KB
    const int tid  = threadIdx.x;
    const int lane = tid & 63;
    const int wave = tid >> 6;
    const int wm   = (wave >> 1) * 64;
    const int wn   = (wave & 1) * 64;
    const int lrow = lane & 15;
    const int q    = lane >> 4;

    const int bm  = blockIdx.x * TM;
    const int bn  = blockIdx.y * TN;
    const int bz  = blockIdx.z;
    const int kb  = bz * KSPLIT;

    // staging: wave w covers rows w*32 + (lane>>3) + 8i, chunk lane&7.
    // source chunk pre-swizzled: g = (lane&7) ^ (sr&7), sr&7 == lane>>3.
    const int sr  = wave * 32 + (lane >> 3);
    const int sco = (((lane & 7) ^ (lane >> 3)) << 3);   // ushort offset
    const ushort* gA = A + (size_t)(bm + sr) * IN_DIM + kb + sco;
    const ushort* gB = B + (size_t)(bn + sr) * IN_DIM + kb + sco;
    ushort* lA = As + wave * 2048;
    ushort* lB = Bs + wave * 2048;

    // read-side swizzled chunk offset (ushorts): step s flips bit2 (^32)
    const int c0u = ((q ^ (lrow & 7)) << 3);

    fx4 acc[4][4] = {};

    for (int k0 = 0; k0 < KSPLIT; k0 += BK) {
#pragma unroll
        for (int i = 0; i < 4; ++i)
            GLDS(gA + k0 + (size_t)i * 8 * IN_DIM, lA + i * 512);
#pragma unroll
        for (int i = 0; i < 4; ++i)
            GLDS(gB + k0 + (size_t)i * 8 * IN_DIM, lB + i * 512);
        __syncthreads();

#pragma unroll
        for (int s = 0; s < 2; ++s) {
            const int co = c0u ^ (s << 5);
            bf16x8 af[4], bfr[4];
#pragma unroll
            for (int mi = 0; mi < 4; ++mi)
                af[mi] = *reinterpret_cast<const bf16x8*>(As + (wm + mi * 16 + lrow) * BK + co);
#pragma unroll
            for (int ni = 0; ni < 4; ++ni)
                bfr[ni] = *reinterpret_cast<const bf16x8*>(Bs + (wn + ni * 16 + lrow) * BK + co);
#pragma unroll
            for (int mi = 0; mi < 4; ++mi)
#pragma unroll
                for (int ni = 0; ni < 4; ++ni)
                    acc[mi][ni] = __builtin_amdgcn_mfma_f32_16x16x32_bf16(af[mi], bfr[ni], acc[mi][ni], 0, 0, 0);
        }
        __syncthreads();
    }

    ushort* Pz = P + (size_t)bz * MM * OUT_DIM;
#pragma unroll
    for (int mi = 0; mi < 4; ++mi)
#pragma unroll
        for (int ni = 0; ni < 4; ++ni) {
            int r = bm + wm + mi * 16 + q * 4;
            int c = bn + wn + ni * 16 + lrow;
#pragma unroll
            for (int v = 0; v < 4; ++v)
                Pz[(size_t)(r + v) * OUT_DIM + c] = f2bf(acc[mi][ni][v]);
        }
}

// ---------------------------------------------------------------------------
// K6: parallel prologue — lanes 0..9 of wave 0 load idx/beta, dedupe via
// shfl (dup -> weight 0 == reference set semantics), softmax via shfl over
// 16 lanes.  Then all 256 threads gather: out = sum_t w_t*(P0[j_t]+P1[j_t]).
// ---------------------------------------------------------------------------
__global__ __launch_bounds__(256) void k_aggregate(const ushort* __restrict__ P,
                                                   const float* __restrict__ nalpha,
                                                   const float* __restrict__ nbeta,
                                                   const int* __restrict__ nidx,
                                                   float* __restrict__ outp) {
    int row = blockIdx.x;
    __shared__ int   s_idx[NSAMP];
    __shared__ float s_w[NSAMP];
    if (threadIdx.x < 16) {
        int t = threadIdx.x;
        int j = (t < NSAMP) ? nidx[row * NSAMP + t] : -1;
        float score = -INFINITY;
        if (t < NSAMP) {
            float x = nalpha[row] + nbeta[j];
            score = x > 0.f ? x : 0.2f * x;
        }
        bool dup = false;
#pragma unroll
        for (int sIdx = 0; sIdx < NSAMP; ++sIdx) {
            int js = __shfl(j, sIdx, 16);
            if (sIdx < t && js == j) dup = true;
        }
        float mx = score;
#pragma unroll
        for (int off = 8; off > 0; off >>= 1) {
            float o = __shfl_xor(mx, off, 16);
            mx = o > mx ? o : mx;
        }
        float e = (t < NSAMP && !dup) ? expf(score - mx) : 0.f;
        float sum = e;
#pragma unroll
        for (int off = 8; off > 0; off >>= 1) sum += __shfl_xor(sum, off, 16);
        if (t < NSAMP) {
            s_idx[t] = j;
            s_w[t]   = e / sum;
        }
    }
    __syncthreads();
    int col = threadIdx.x * 4;
    float ax = 0.f, ay = 0.f, az = 0.f, aw = 0.f;
#pragma unroll
    for (int t = 0; t < NSAMP; ++t) {
        float w = s_w[t];
        size_t off = (size_t)s_idx[t] * OUT_DIM + col;
        ushort4 u0 = *reinterpret_cast<const ushort4*>(P + off);
        ushort4 u1 = *reinterpret_cast<const ushort4*>(P + (size_t)MM * OUT_DIM + off);
        ax += w * (bf2f(u0.x) + bf2f(u1.x));
        ay += w * (bf2f(u0.y) + bf2f(u1.y));
        az += w * (bf2f(u0.z) + bf2f(u1.z));
        aw += w * (bf2f(u0.w) + bf2f(u1.w));
    }
    float4 o; o.x = ax; o.y = ay; o.z = az; o.w = aw;
    *reinterpret_cast<float4*>(outp + (size_t)row * OUT_DIM + col) = o;
}

// ---------------------------------------------------------------------------
extern "C" void kernel_launch(void* const* d_in, const int* in_sizes, int n_in,
                              void* d_out, int out_size, void* d_ws, size_t ws_size,
                              hipStream_t stream) {
    const float* node_f  = (const float*)d_in[0];  // 4096 x 4096
    const float* neigh_f = (const float*)d_in[1];  // 8192 x 4096
    const float* W       = (const float*)d_in[2];  // 1024 x 4096
    const float* att     = (const float*)d_in[3];  // 2048
    const int*   nidx    = (const int*)d_in[4];    // 4096 x 10
    float* outp = (float*)d_out;                   // 4096 x 1024 fp32

    char* ws = (char*)d_ws;
    ushort* Abf = (ushort*)ws;                     // 64 MB bf16 A
    ushort* Wbf = (ushort*)(ws + 67108864);        // 8 MB  bf16 W
    ushort* P   = (ushort*)(ws + 75497472);        // 2 x 16 MB bf16 partials
    float*  v1     = (float*)(ws + 109051904);
    float*  v2     = v1 + IN_DIM;
    float*  nalpha = v2 + IN_DIM;
    float*  nbeta  = nalpha + NN;

    hipMemsetAsync(v1, 0, 2 * IN_DIM * sizeof(float), stream);

    k_attvec   <<<dim3(16, 64),          256, 0, stream>>>(W, att, v1, v2, Wbf);
    k_rows     <<<(NN + MM) / 4,         256, 0, stream>>>(node_f, neigh_f, v1, v2, nalpha, nbeta, Abf);
    k_gemm     <<<dim3(64, 8, 2),        256, 0, stream>>>(Abf, Wbf, P);
    k_aggregate<<<NN,                    256, 0, stream>>>(P, nalpha, nbeta, nidx, outp);
}

// Round 5
// 367.470 us; speedup vs baseline: 1.1158x; 1.0053x over previous
//
#include <hip/hip_runtime.h>

#define IN_DIM  4096
#define OUT_DIM 1024
#define NN      4096
#define MM      8192
#define NSAMP   10

typedef __bf16 bf16x8 __attribute__((ext_vector_type(8)));
typedef float  fx4    __attribute__((ext_vector_type(4)));

__device__ __forceinline__ ushort f2bf(float f) {
    union { float f; unsigned u; } v; v.f = f;
    unsigned u = v.u;
    return (ushort)((u + 0x7FFFu + ((u >> 16) & 1u)) >> 16);
}
__device__ __forceinline__ float bf2f(ushort u) {
    union { unsigned u; float f; } v; v.u = ((unsigned)u) << 16;
    return v.f;
}

// async global->LDS, 16B per lane; LDS dest = wave-uniform base + lane*16
#define GLDS(g, l) __builtin_amdgcn_global_load_lds(                           \
    (const __attribute__((address_space(1))) unsigned*)(g),                    \
    (__attribute__((address_space(3))) unsigned*)(l), 16, 0, 0)

// ---------------------------------------------------------------------------
// K1: v1[k] = sum_o a1[o]*W[o,k];  v2[k] = sum_o a2[o]*W[o,k]
//     + fused: Wbf = bf16(W)  (W read exactly once here)
// grid (16,64): x = k-tile of 256, y = o-slice of 16; atomicAdd partials.
// ---------------------------------------------------------------------------
__global__ __launch_bounds__(256) void k_attvec(const float* __restrict__ W,
                                                const float* __restrict__ att,
                                                float* __restrict__ v1,
                                                float* __restrict__ v2,
                                                ushort* __restrict__ Wbf) {
    int k  = blockIdx.x * 256 + threadIdx.x;
    int o0 = blockIdx.y * 16;
    float s1 = 0.f, s2 = 0.f;
#pragma unroll
    for (int o = o0; o < o0 + 16; ++o) {
        float w = W[(size_t)o * IN_DIM + k];
        Wbf[(size_t)o * IN_DIM + k] = f2bf(w);
        s1 += att[o] * w;
        s2 += att[OUT_DIM + o] * w;
    }
    atomicAdd(&v1[k], s1);
    atomicAdd(&v2[k], s2);
}

// ---------------------------------------------------------------------------
// K2 (fused): one WAVE per row over NN + MM rows (4 rows per 256-thr block).
//   row < NN:  nalpha[row] = node_f[row,:] . v1
//   row >= NN: j = row-NN;  nbeta[j] = neigh_f[j,:] . v2  AND Abf[j,:] = bf16
// R4 lesson: compiler didn't unroll the strided loop (VGPR=12, ~1 load in
// flight/wave -> latency-bound at 1.8 TB/s). Explicit compile-time 4x4
// unroll: 8 independent float4 loads per group, VGPR stays < 64 (occupancy
// cliff at 64 per m69).
// ---------------------------------------------------------------------------
__global__ __launch_bounds__(256) void k_rows(const float* __restrict__ node_f,
                                              const float* __restrict__ neigh_f,
                                              const float* __restrict__ v1,
                                              const float* __restrict__ v2,
                                              float* __restrict__ nalpha,
                                              float* __restrict__ nbeta,
                                              ushort* __restrict__ Abf) {
    int row  = blockIdx.x * 4 + (threadIdx.x >> 6);
    int lane = threadIdx.x & 63;
    float s = 0.f;
    if (row < NN) {
        const float4* xr = reinterpret_cast<const float4*>(node_f + (size_t)row * IN_DIM);
        const float4* vr = reinterpret_cast<const float4*>(v1);
#pragma unroll
        for (int ii = 0; ii < 4; ++ii) {
            float4 a0 = xr[lane + (ii * 4 + 0) * 64];
            float4 a1 = xr[lane + (ii * 4 + 1) * 64];
            float4 a2 = xr[lane + (ii * 4 + 2) * 64];
            float4 a3 = xr[lane + (ii * 4 + 3) * 64];
            float4 b0 = vr[lane + (ii * 4 + 0) * 64];
            float4 b1 = vr[lane + (ii * 4 + 1) * 64];
            float4 b2 = vr[lane + (ii * 4 + 2) * 64];
            float4 b3 = vr[lane + (ii * 4 + 3) * 64];
            s += a0.x * b0.x + a0.y * b0.y + a0.z * b0.z + a0.w * b0.w;
            s += a1.x * b1.x + a1.y * b1.y + a1.z * b1.z + a1.w * b1.w;
            s += a2.x * b2.x + a2.y * b2.y + a2.z * b2.z + a2.w * b2.w;
            s += a3.x * b3.x + a3.y * b3.y + a3.z * b3.z + a3.w * b3.w;
        }
    } else {
        int j = row - NN;
        const float4* xr = reinterpret_cast<const float4*>(neigh_f + (size_t)j * IN_DIM);
        const float4* vr = reinterpret_cast<const float4*>(v2);
        ushort4* yr = reinterpret_cast<ushort4*>(Abf + (size_t)j * IN_DIM);
#pragma unroll
        for (int ii = 0; ii < 4; ++ii) {
            float4 a0 = xr[lane + (ii * 4 + 0) * 64];
            float4 a1 = xr[lane + (ii * 4 + 1) * 64];
            float4 a2 = xr[lane + (ii * 4 + 2) * 64];
            float4 a3 = xr[lane + (ii * 4 + 3) * 64];
            float4 b0 = vr[lane + (ii * 4 + 0) * 64];
            float4 b1 = vr[lane + (ii * 4 + 1) * 64];
            float4 b2 = vr[lane + (ii * 4 + 2) * 64];
            float4 b3 = vr[lane + (ii * 4 + 3) * 64];
            s += a0.x * b0.x + a0.y * b0.y + a0.z * b0.z + a0.w * b0.w;
            s += a1.x * b1.x + a1.y * b1.y + a1.z * b1.z + a1.w * b1.w;
            s += a2.x * b2.x + a2.y * b2.y + a2.z * b2.z + a2.w * b2.w;
            s += a3.x * b3.x + a3.y * b3.y + a3.z * b3.z + a3.w * b3.w;
            ushort4 o0, o1, o2, o3;
            o0.x = f2bf(a0.x); o0.y = f2bf(a0.y); o0.z = f2bf(a0.z); o0.w = f2bf(a0.w);
            o1.x = f2bf(a1.x); o1.y = f2bf(a1.y); o1.z = f2bf(a1.z); o1.w = f2bf(a1.w);
            o2.x = f2bf(a2.x); o2.y = f2bf(a2.y); o2.z = f2bf(a2.z); o2.w = f2bf(a2.w);
            o3.x = f2bf(a3.x); o3.y = f2bf(a3.y); o3.z = f2bf(a3.z); o3.w = f2bf(a3.w);
            yr[lane + (ii * 4 + 0) * 64] = o0;
            yr[lane + (ii * 4 + 1) * 64] = o1;
            yr[lane + (ii * 4 + 2) * 64] = o2;
            yr[lane + (ii * 4 + 3) * 64] = o3;
        }
    }
#pragma unroll
    for (int off = 32; off > 0; off >>= 1) s += __shfl_down(s, off, 64);
    if (lane == 0) {
        if (row < NN) nalpha[row] = s; else nbeta[row - NN] = s;
    }
}

// ---------------------------------------------------------------------------
// K5: split-K x2 GEMM — r0 structure (128x128 tile, 4 waves 2x2 of 64x64,
// 256 thr, ~4 blocks/CU) + BK=64 + conflict-free LDS swizzle.
// Block mapping: DEFAULT dim3(64,8,2), x = M-tile fastest. Linear id =
// bx + 64*by + 512*bz -> XCD = bx&7: each 512KB A-panel is read by exactly
// ONE XCD (all by,bz of that bx residue) -> A (64 MB, the big operand)
// fetched from HBM once. B (8 MB) broadcast-fetched; L2 absorbs most.
// (Round-3 lesson: the inverted mapping fetched A 4x = 271 MB, -15% perf.)
//  * BK=64 (32 KiB LDS): halves syncthreads/vmcnt-drain count (32 K-tiles).
//  * Conflict-free XOR swizzle (verified 0 conflict cycles r3): LDS rows are
//    128 B = 8 x 16B chunks; LDS(r,c) holds global chunk c^(r&7). Stage:
//    linear GLDS dest, source chunk = (lane&7)^(lane>>3). Read: chunk
//    (q|s*4)^(lrow&7) -> 8-lane groups hit 8 distinct chunks.
// Fragment layouts (HW-verified, learn_hip m89):
//   A/B operand: outer = lane&15, k = (lane>>4)*8 + j  (k-step s adds s*32)
//   C/D:         col   = lane&15, row = (lane>>4)*4 + reg
// ---------------------------------------------------------------------------
#define TM 128
#define TN 128
#define BK 64
#define KSPLIT (IN_DIM / 2)

__global__ __launch_bounds__(256, 4) void k_gemm(const ushort* __restrict__ A,
                                                 const ushort* __restrict__ B,
                                                 ushort* __restrict__ P) {
    __shared__ __align__(16) ushort As[TM * BK];   // 16 KB
    __shared__ __align__(16) ushort Bs[TN * BK];   // 16 KB
    const int tid  = threadIdx.x;
    const int lane = tid & 63;
    const int wave = tid >> 6;
    const int wm   = (wave >> 1) * 64;
    const int wn   = (wave & 1) * 64;
    const int lrow = lane & 15;
    const int q    = lane >> 4;

    const int bm  = blockIdx.x * TM;
    const int bn  = blockIdx.y * TN;
    const int bz  = blockIdx.z;
    const int kb  = bz * KSPLIT;

    // staging: wave w covers rows w*32 + (lane>>3) + 8i, chunk lane&7.
    // source chunk pre-swizzled: g = (lane&7) ^ (sr&7), sr&7 == lane>>3.
    const int sr  = wave * 32 + (lane >> 3);
    const int sco = (((lane & 7) ^ (lane >> 3)) << 3);   // ushort offset
    const ushort* gA = A + (size_t)(bm + sr) * IN_DIM + kb + sco;
    const ushort* gB = B + (size_t)(bn + sr) * IN_DIM + kb + sco;
    ushort* lA = As + wave * 2048;
    ushort* lB = Bs + wave * 2048;

    // read-side swizzled chunk offset (ushorts): step s flips bit2 (^32)
    const int c0u = ((q ^ (lrow & 7)) << 3);

    fx4 acc[4][4] = {};

    for (int k0 = 0; k0 < KSPLIT; k0 += BK) {
#pragma unroll
        for (int i = 0; i < 4; ++i)
            GLDS(gA + k0 + (size_t)i * 8 * IN_DIM, lA + i * 512);
#pragma unroll
        for (int i = 0; i < 4; ++i)
            GLDS(gB + k0 + (size_t)i * 8 * IN_DIM, lB + i * 512);
        __syncthreads();

#pragma unroll
        for (int s = 0; s < 2; ++s) {
            const int co = c0u ^ (s << 5);
            bf16x8 af[4], bfr[4];
#pragma unroll
            for (int mi = 0; mi < 4; ++mi)
                af[mi] = *reinterpret_cast<const bf16x8*>(As + (wm + mi * 16 + lrow) * BK + co);
#pragma unroll
            for (int ni = 0; ni < 4; ++ni)
                bfr[ni] = *reinterpret_cast<const bf16x8*>(Bs + (wn + ni * 16 + lrow) * BK + co);
#pragma unroll
            for (int mi = 0; mi < 4; ++mi)
#pragma unroll
                for (int ni = 0; ni < 4; ++ni)
                    acc[mi][ni] = __builtin_amdgcn_mfma_f32_16x16x32_bf16(af[mi], bfr[ni], acc[mi][ni], 0, 0, 0);
        }
        __syncthreads();
    }

    ushort* Pz = P + (size_t)bz * MM * OUT_DIM;
#pragma unroll
    for (int mi = 0; mi < 4; ++mi)
#pragma unroll
        for (int ni = 0; ni < 4; ++ni) {
            int r = bm + wm + mi * 16 + q * 4;
            int c = bn + wn + ni * 16 + lrow;
#pragma unroll
            for (int v = 0; v < 4; ++v)
                Pz[(size_t)(r + v) * OUT_DIM + c] = f2bf(acc[mi][ni][v]);
        }
}

// ---------------------------------------------------------------------------
// K6: parallel prologue — lanes 0..9 of wave 0 load idx/beta, dedupe via
// shfl (dup -> weight 0 == reference set semantics), softmax via shfl over
// 16 lanes.  Then all 256 threads gather: out = sum_t w_t*(P0[j_t]+P1[j_t]).
// ---------------------------------------------------------------------------
__global__ __launch_bounds__(256) void k_aggregate(const ushort* __restrict__ P,
                                                   const float* __restrict__ nalpha,
                                                   const float* __restrict__ nbeta,
                                                   const int* __restrict__ nidx,
                                                   float* __restrict__ outp) {
    int row = blockIdx.x;
    __shared__ int   s_idx[NSAMP];
    __shared__ float s_w[NSAMP];
    if (threadIdx.x < 16) {
        int t = threadIdx.x;
        int j = (t < NSAMP) ? nidx[row * NSAMP + t] : -1;
        float score = -INFINITY;
        if (t < NSAMP) {
            float x = nalpha[row] + nbeta[j];
            score = x > 0.f ? x : 0.2f * x;
        }
        bool dup = false;
#pragma unroll
        for (int sIdx = 0; sIdx < NSAMP; ++sIdx) {
            int js = __shfl(j, sIdx, 16);
            if (sIdx < t && js == j) dup = true;
        }
        float mx = score;
#pragma unroll
        for (int off = 8; off > 0; off >>= 1) {
            float o = __shfl_xor(mx, off, 16);
            mx = o > mx ? o : mx;
        }
        float e = (t < NSAMP && !dup) ? expf(score - mx) : 0.f;
        float sum = e;
#pragma unroll
        for (int off = 8; off > 0; off >>= 1) sum += __shfl_xor(sum, off, 16);
        if (t < NSAMP) {
            s_idx[t] = j;
            s_w[t]   = e / sum;
        }
    }
    __syncthreads();
    int col = threadIdx.x * 4;
    float ax = 0.f, ay = 0.f, az = 0.f, aw = 0.f;
#pragma unroll
    for (int t = 0; t < NSAMP; ++t) {
        float w = s_w[t];
        size_t off = (size_t)s_idx[t] * OUT_DIM + col;
        ushort4 u0 = *reinterpret_cast<const ushort4*>(P + off);
        ushort4 u1 = *reinterpret_cast<const ushort4*>(P + (size_t)MM * OUT_DIM + off);
        ax += w * (bf2f(u0.x) + bf2f(u1.x));
        ay += w * (bf2f(u0.y) + bf2f(u1.y));
        az += w * (bf2f(u0.z) + bf2f(u1.z));
        aw += w * (bf2f(u0.w) + bf2f(u1.w));
    }
    float4 o; o.x = ax; o.y = ay; o.z = az; o.w = aw;
    *reinterpret_cast<float4*>(outp + (size_t)row * OUT_DIM + col) = o;
}

// ---------------------------------------------------------------------------
extern "C" void kernel_launch(void* const* d_in, const int* in_sizes, int n_in,
                              void* d_out, int out_size, void* d_ws, size_t ws_size,
                              hipStream_t stream) {
    const float* node_f  = (const float*)d_in[0];  // 4096 x 4096
    const float* neigh_f = (const float*)d_in[1];  // 8192 x 4096
    const float* W       = (const float*)d_in[2];  // 1024 x 4096
    const float* att     = (const float*)d_in[3];  // 2048
    const int*   nidx    = (const int*)d_in[4];    // 4096 x 10
    float* outp = (float*)d_out;                   // 4096 x 1024 fp32

    char* ws = (char*)d_ws;
    ushort* Abf = (ushort*)ws;                     // 64 MB bf16 A
    ushort* Wbf = (ushort*)(ws + 67108864);        // 8 MB  bf16 W
    ushort* P   = (ushort*)(ws + 75497472);        // 2 x 16 MB bf16 partials
    float*  v1     = (float*)(ws + 109051904);
    float*  v2     = v1 + IN_DIM;
    float*  nalpha = v2 + IN_DIM;
    float*  nbeta  = nalpha + NN;

    hipMemsetAsync(v1, 0, 2 * IN_DIM * sizeof(float), stream);

    k_attvec   <<<dim3(16, 64),          256, 0, stream>>>(W, att, v1, v2, Wbf);
    k_rows     <<<(NN + MM) / 4,         256, 0, stream>>>(node_f, neigh_f, v1, v2, nalpha, nbeta, Abf);
    k_gemm     <<<dim3(64, 8, 2),        256, 0, stream>>>(Abf, Wbf, P);
    k_aggregate<<<NN,                    256, 0, stream>>>(P, nalpha, nbeta, nidx, outp);
}